// Round 17
// baseline (125.401 us; speedup 1.0000x reference)
//
#include <hip/hip_runtime.h>
#include <hip/hip_bf16.h>

#define B_ 16
#define N_ 8192
#define C_ 512
#define H_ 8
#define CH_ 32
#define NT_ 32   // tiles per block (256 rows / 8 rows-per-tile)

// ws float layout:
//   [512, 4608)       qk[h][c]  (8 x 512)
//   [4608, 4736)      l[b][h] atomic sums (16 x 8)
//   [4736, 70272)     aa[b][h][c] atomic-accumulated weighted sums (16 x 8 x 512)
#define WS_QK   512
#define WS_L    4608
#define WS_AA   4736

// k_main saga (resolved): the COMPILER inserted a conservative vmcnt(0) before
// its own visible ds_read of the global_load_lds destination, collapsing any
// FIFO to synchronous (~4.2TB/s cap, R3-R13). Fix (probe-verified 63->44us/
// pass): DMA FIFO depth-3 + consumption via inline-asm ds_read_b128 with
// lgkmcnt(0) INSIDE the asm on AS(3) pointers. R17: fuse proj1+proj2 into one
// 16-block kernel (kills one launch gap + the pp round-trip).

#if defined(__has_builtin)
#if __has_builtin(__builtin_amdgcn_global_load_lds)
#define HAVE_GLD 1
#endif
#endif

#ifdef HAVE_GLD
__device__ __forceinline__ void dma16(const float* g, float* l) {
    __builtin_amdgcn_global_load_lds(
        (const __attribute__((address_space(1))) unsigned int*)g,
        (__attribute__((address_space(3))) unsigned int*)l, 16, 0, 0);
}
#else
__device__ __forceinline__ void dma16(const float* g, float* l) {
    *(float4*)(l + 4 * (threadIdx.x & 63)) = *(const float4*)g;
}
#endif

// synchronous LDS read pair, invisible to the compiler's waitcnt/alias passes
__device__ __forceinline__ void lds_read2(float4& v0, float4& v1,
                                          const float* p0, const float* p1) {
    const __attribute__((address_space(3))) float* a0 =
        (const __attribute__((address_space(3))) float*)p0;
    const __attribute__((address_space(3))) float* a1 =
        (const __attribute__((address_space(3))) float*)p1;
    asm volatile("ds_read_b128 %0, %2\n\t"
                 "ds_read_b128 %1, %3\n\t"
                 "s_waitcnt lgkmcnt(0)"
                 : "=&v"(v0), "=&v"(v1)
                 : "v"(a0), "v"(a1));
}

// ---------------- K1: fused prep ----------------
__global__ void k_prep(const float* __restrict__ cls, const float* __restrict__ Wq,
                       const float* __restrict__ Wk, float* __restrict__ ws) {
    __shared__ float red[256];
    __shared__ float qf[64];
    int t = threadIdx.x;
    int h = blockIdx.x >> 3, cc = blockIdx.x & 7;

    {
        float4 z = {0.f, 0.f, 0.f, 0.f};
        *(float4*)(ws + WS_AA + blockIdx.x * 1024 + 4 * t) = z;
        if (blockIdx.x == 0 && t < 128) ws[WS_L + t] = 0.f;
    }

    {
        int j = t & 63, q = t >> 6;
        const float* wq = Wq + h * 64 + j;
        float p = 0.f;
#pragma unroll 16
        for (int c = q * 128; c < q * 128 + 128; ++c)
            p = fmaf(cls[c], wq[(size_t)c * C_], p);
        red[t] = p;
    }
    __syncthreads();
    if (t < 64) qf[t] = (red[t] + red[t + 64] + red[t + 128] + red[t + 192]) * 0.125f;
    __syncthreads();

    {
        int cl = t & 63, q = t >> 6;
        int c = cc * 64 + cl;
        const float4* wk = (const float4*)(Wk + (size_t)c * C_ + h * 64 + q * 16);
        const float4* qv = (const float4*)(qf + q * 16);
        float p = 0.f;
#pragma unroll
        for (int u = 0; u < 4; ++u) {
            float4 w4 = wk[u], q4 = qv[u];
            p = fmaf(w4.x, q4.x, p); p = fmaf(w4.y, q4.y, p);
            p = fmaf(w4.z, q4.z, p); p = fmaf(w4.w, q4.w, p);
        }
        red[t] = p;
    }
    __syncthreads();
    if (t < 64)
        ws[WS_QK + h * C_ + cc * 64 + t] = red[t] + red[t + 64] + red[t + 128] + red[t + 192];
}

// ---------------- K2: main streaming pass (DMA FIFO + hidden LDS reads) ----------------
__global__ __launch_bounds__(256) void k_main(const float* __restrict__ x,
                                              float* __restrict__ ws, int CH) {
    __shared__ float smem[4][4][1024];   // [wave][buf][2 rows]; 64 KB
    __shared__ float sl[8];

    int blk = blockIdx.x;
    int b = blk / CH, chunk = blk % CH;
    int lane = threadIdx.x & 63, wave = threadIdx.x >> 6;
    int rpb = N_ / CH;            // 256
    int n0 = chunk * rpb;
    const float* xp = x + ((size_t)b * N_ + n0) * C_;
    const float* gw = xp + (size_t)(2 * wave) * C_;   // wave's rows in tile 0

    const float* qk = ws + WS_QK;
    int lo = 4 * lane, hi = 256 + 4 * lane;
    float qr[8][8];
#pragma unroll
    for (int h = 0; h < 8; ++h) {
        float4 a = *(const float4*)(qk + h * C_ + lo);
        float4 bb = *(const float4*)(qk + h * C_ + hi);
        qr[h][0] = a.x;  qr[h][1] = a.y;  qr[h][2] = a.z;  qr[h][3] = a.w;
        qr[h][4] = bb.x; qr[h][5] = bb.y; qr[h][6] = bb.z; qr[h][7] = bb.w;
    }

    float acc[8][8];
#pragma unroll
    for (int h = 0; h < 8; ++h)
#pragma unroll
        for (int j = 0; j < 8; ++j) acc[h][j] = 0.f;
    float lsum = 0.f;

    auto row_body = [&](const float4& v0, const float4& v1) {
        float xv[8] = {v0.x, v0.y, v0.z, v0.w, v1.x, v1.y, v1.z, v1.w};
        float p[8];
#pragma unroll
        for (int h = 0; h < 8; ++h) {
            float s = xv[0] * qr[h][0];
#pragma unroll
            for (int j = 1; j < 8; ++j) s = fmaf(xv[j], qr[h][j], s);
            p[h] = s;
        }
        int b0 = lane & 1, b1 = lane & 2, b2 = lane & 4;
        float t4[4];
#pragma unroll
        for (int i = 0; i < 4; ++i) {
            float send = b0 ? p[i] : p[i + 4];
            float recv = __shfl_xor(send, 1, 64);
            t4[i] = (b0 ? p[i + 4] : p[i]) + recv;
        }
        float u2[2];
#pragma unroll
        for (int i = 0; i < 2; ++i) {
            float send = b1 ? t4[i] : t4[i + 2];
            float recv = __shfl_xor(send, 2, 64);
            u2[i] = (b1 ? t4[i + 2] : t4[i]) + recv;
        }
        float send = b2 ? u2[0] : u2[1];
        float recv = __shfl_xor(send, 4, 64);
        float v = (b2 ? u2[1] : u2[0]) + recv;
        v += __shfl_xor(v, 8, 64);
        v += __shfl_xor(v, 16, 64);
        v += __shfl_xor(v, 32, 64);
        float e = __expf(v);   // logits ~N(0,0.2): un-normalized softmax safe
        lsum += e;
#pragma unroll
        for (int h = 0; h < 8; ++h) {
            int src = ((h & 4) >> 2) | (h & 2) | ((h & 1) << 2);
            float wf = __int_as_float(__builtin_amdgcn_readlane(__float_as_int(e), src));
#pragma unroll
            for (int j = 0; j < 8; ++j) acc[h][j] = fmaf(wf, xv[j], acc[h][j]);
        }
    };

    // prologue: stage tiles 0,1,2 (12 outstanding DMAs)
#pragma unroll
    for (int T = 0; T < 3; ++T) {
        const float* g = gw + (size_t)T * 8 * C_;
        float* d = &smem[wave][T][0];
#pragma unroll
        for (int k = 0; k < 4; ++k)
            dma16(g + k * 256 + lo, d + k * 256);
    }

#pragma unroll 1
    for (int T = 0; T < NT_; ++T) {
        {
            int tn = T + 3 < NT_ ? T + 3 : NT_ - 1;
            const float* g = gw + (size_t)tn * 8 * C_;
            float* d = &smem[wave][(T + 3) & 3][0];
#pragma unroll
            for (int k = 0; k < 4; ++k)
                dma16(g + k * 256 + lo, d + k * 256);
        }
        asm volatile("s_waitcnt vmcnt(12)" ::: "memory");  // tile T landed
        __builtin_amdgcn_sched_barrier(0);
        float* cur = &smem[wave][T & 3][0];
#pragma unroll
        for (int r = 0; r < 2; ++r) {
            float4 v0, v1;
            lds_read2(v0, v1, cur + r * 512 + lo, cur + r * 512 + hi);
            row_body(v0, v1);
        }
    }
    asm volatile("s_waitcnt vmcnt(0)" ::: "memory");  // drain tail dups

    float lw[8];
#pragma unroll
    for (int h = 0; h < 8; ++h) {
        int src = ((h & 4) >> 2) | (h & 2) | ((h & 1) << 2);
        lw[h] = __int_as_float(__builtin_amdgcn_readlane(__float_as_int(lsum), src));
    }

    __syncthreads();
    float* sacc = &smem[0][0][0];   // reuse (8*512 floats)
    for (int w = 0; w < 4; ++w) {
        if (wave == w) {
#pragma unroll
            for (int h = 0; h < 8; ++h) {
                float4 vlo = {acc[h][0], acc[h][1], acc[h][2], acc[h][3]};
                float4 vhi = {acc[h][4], acc[h][5], acc[h][6], acc[h][7]};
                float4* d0 = (float4*)&sacc[h * C_ + lo];
                float4* d1 = (float4*)&sacc[h * C_ + hi];
                if (w == 0) { d0[0] = vlo; d1[0] = vhi; }
                else {
                    float4 a0 = d0[0], a1 = d1[0];
                    a0.x += vlo.x; a0.y += vlo.y; a0.z += vlo.z; a0.w += vlo.w;
                    a1.x += vhi.x; a1.y += vhi.y; a1.z += vhi.z; a1.w += vhi.w;
                    d0[0] = a0; d1[0] = a1;
                }
            }
            if (lane == 0) {
#pragma unroll
                for (int h = 0; h < 8; ++h) {
                    if (w == 0) sl[h] = lw[h]; else sl[h] += lw[h];
                }
            }
        }
        __syncthreads();
    }

    float* aa = ws + WS_AA + b * 4096;
#pragma unroll 16
    for (int k = threadIdx.x; k < 4096; k += 256)
        atomicAdd(&aa[k], sacc[k]);
    if (threadIdx.x < 8)
        atomicAdd(&ws[WS_L + b * 8 + threadIdx.x], sl[threadIdx.x]);
}

// ---------------- K3: fused projection: out[b,:] = ((1/l)*aa[b] @ Wv) @ Wp + bp ----
// One block per batch row b. Stage 1: pooled[o] (512) into LDS; stage 2: out.
__global__ __launch_bounds__(256) void k_proj(const float* __restrict__ ws,
                                              const float* __restrict__ Wv,
                                              const float* __restrict__ Wp,
                                              const float* __restrict__ bp,
                                              float* __restrict__ out) {
    __shared__ float pl[512];
    int b = blockIdx.x, t = threadIdx.x;
    const float* aab = ws + WS_AA + b * 4096;

#pragma unroll 1
    for (int oo = 0; oo < 2; ++oo) {
        int o = t + oo * 256;
        int h = o >> 6;
        const float* ah = aab + h * C_;
        float Li = 1.f / ws[WS_L + b * 8 + h];
        float s = 0.f;
#pragma unroll 16
        for (int c = 0; c < 512; ++c)
            s = fmaf(ah[c], Wv[(size_t)c * C_ + o], s);
        pl[o] = s * Li;
    }
    __syncthreads();

#pragma unroll 1
    for (int oo = 0; oo < 2; ++oo) {
        int o = t + oo * 256;
        float s = bp[o];
#pragma unroll 16
        for (int c = 0; c < 512; ++c)
            s = fmaf(pl[c], Wp[(size_t)c * C_ + o], s);
        out[(size_t)b * C_ + o] = s;
    }
}

extern "C" void kernel_launch(void* const* d_in, const int* in_sizes, int n_in,
                              void* d_out, int out_size, void* d_ws, size_t ws_size,
                              hipStream_t stream) {
    const float* x   = (const float*)d_in[0];
    const float* cls = (const float*)d_in[1];
    const float* Wq  = (const float*)d_in[2];
    const float* Wk  = (const float*)d_in[3];
    const float* Wv  = (const float*)d_in[4];
    const float* Wp  = (const float*)d_in[5];
    const float* bp  = (const float*)d_in[6];
    float* out = (float*)d_out;
    float* ws  = (float*)d_ws;

    k_prep<<<64, 256, 0, stream>>>(cls, Wq, Wk, ws);
    k_main<<<B_ * CH_, 256, 0, stream>>>(x, ws, CH_);
    k_proj<<<B_, 256, 0, stream>>>(ws, Wv, Wp, bp, out);
}

// Round 18
// 94.291 us; speedup vs baseline: 1.3299x; 1.3299x over previous
//
#include <hip/hip_runtime.h>
#include <hip/hip_bf16.h>

#define B_ 16
#define N_ 8192
#define C_ 512
#define H_ 8
#define CH_ 32
#define NT_ 32   // tiles per block (256 rows / 8 rows-per-tile)

// ws float layout:
//   [512, 4608)       qk[h][c]  (8 x 512)
//   [4608, 4736)      l[b][h] atomic sums (16 x 8)
//   [4736, 70272)     aa[b][h][c] atomic-accumulated weighted sums (16 x 8 x 512)
//   [70272, 86656)    pp[half][b][o] partial pooled (2 x 16 x 512)
#define WS_QK   512
#define WS_L    4608
#define WS_AA   4736
#define WS_PP   70272

// R16 configuration (measured 94.99us, best): compiler-waitcnt bypass in
// k_main (DMA FIFO depth-3 + asm ds_read) and SPLIT projection kernels.
// R17 fused proj into 16 blocks -> 125us (parallelism loss >> gap savings);
// R18 reverts to the measured optimum. Tail kernels: parallelism > fusion.

#if defined(__has_builtin)
#if __has_builtin(__builtin_amdgcn_global_load_lds)
#define HAVE_GLD 1
#endif
#endif

#ifdef HAVE_GLD
__device__ __forceinline__ void dma16(const float* g, float* l) {
    __builtin_amdgcn_global_load_lds(
        (const __attribute__((address_space(1))) unsigned int*)g,
        (__attribute__((address_space(3))) unsigned int*)l, 16, 0, 0);
}
#else
__device__ __forceinline__ void dma16(const float* g, float* l) {
    *(float4*)(l + 4 * (threadIdx.x & 63)) = *(const float4*)g;
}
#endif

// synchronous LDS read pair, invisible to the compiler's waitcnt/alias passes
__device__ __forceinline__ void lds_read2(float4& v0, float4& v1,
                                          const float* p0, const float* p1) {
    const __attribute__((address_space(3))) float* a0 =
        (const __attribute__((address_space(3))) float*)p0;
    const __attribute__((address_space(3))) float* a1 =
        (const __attribute__((address_space(3))) float*)p1;
    asm volatile("ds_read_b128 %0, %2\n\t"
                 "ds_read_b128 %1, %3\n\t"
                 "s_waitcnt lgkmcnt(0)"
                 : "=&v"(v0), "=&v"(v1)
                 : "v"(a0), "v"(a1));
}

// ---------------- K1: fused prep ----------------
__global__ void k_prep(const float* __restrict__ cls, const float* __restrict__ Wq,
                       const float* __restrict__ Wk, float* __restrict__ ws) {
    __shared__ float red[256];
    __shared__ float qf[64];
    int t = threadIdx.x;
    int h = blockIdx.x >> 3, cc = blockIdx.x & 7;

    {
        float4 z = {0.f, 0.f, 0.f, 0.f};
        *(float4*)(ws + WS_AA + blockIdx.x * 1024 + 4 * t) = z;
        if (blockIdx.x == 0 && t < 128) ws[WS_L + t] = 0.f;
    }

    {
        int j = t & 63, q = t >> 6;
        const float* wq = Wq + h * 64 + j;
        float p = 0.f;
#pragma unroll 16
        for (int c = q * 128; c < q * 128 + 128; ++c)
            p = fmaf(cls[c], wq[(size_t)c * C_], p);
        red[t] = p;
    }
    __syncthreads();
    if (t < 64) qf[t] = (red[t] + red[t + 64] + red[t + 128] + red[t + 192]) * 0.125f;
    __syncthreads();

    {
        int cl = t & 63, q = t >> 6;
        int c = cc * 64 + cl;
        const float4* wk = (const float4*)(Wk + (size_t)c * C_ + h * 64 + q * 16);
        const float4* qv = (const float4*)(qf + q * 16);
        float p = 0.f;
#pragma unroll
        for (int u = 0; u < 4; ++u) {
            float4 w4 = wk[u], q4 = qv[u];
            p = fmaf(w4.x, q4.x, p); p = fmaf(w4.y, q4.y, p);
            p = fmaf(w4.z, q4.z, p); p = fmaf(w4.w, q4.w, p);
        }
        red[t] = p;
    }
    __syncthreads();
    if (t < 64)
        ws[WS_QK + h * C_ + cc * 64 + t] = red[t] + red[t + 64] + red[t + 128] + red[t + 192];
}

// ---------------- K2: main streaming pass (DMA FIFO + hidden LDS reads) ----------------
__global__ __launch_bounds__(256) void k_main(const float* __restrict__ x,
                                              float* __restrict__ ws, int CH) {
    __shared__ float smem[4][4][1024];   // [wave][buf][2 rows]; 64 KB
    __shared__ float sl[8];

    int blk = blockIdx.x;
    int b = blk / CH, chunk = blk % CH;
    int lane = threadIdx.x & 63, wave = threadIdx.x >> 6;
    int rpb = N_ / CH;            // 256
    int n0 = chunk * rpb;
    const float* xp = x + ((size_t)b * N_ + n0) * C_;
    const float* gw = xp + (size_t)(2 * wave) * C_;   // wave's rows in tile 0

    const float* qk = ws + WS_QK;
    int lo = 4 * lane, hi = 256 + 4 * lane;
    float qr[8][8];
#pragma unroll
    for (int h = 0; h < 8; ++h) {
        float4 a = *(const float4*)(qk + h * C_ + lo);
        float4 bb = *(const float4*)(qk + h * C_ + hi);
        qr[h][0] = a.x;  qr[h][1] = a.y;  qr[h][2] = a.z;  qr[h][3] = a.w;
        qr[h][4] = bb.x; qr[h][5] = bb.y; qr[h][6] = bb.z; qr[h][7] = bb.w;
    }

    float acc[8][8];
#pragma unroll
    for (int h = 0; h < 8; ++h)
#pragma unroll
        for (int j = 0; j < 8; ++j) acc[h][j] = 0.f;
    float lsum = 0.f;

    auto row_body = [&](const float4& v0, const float4& v1) {
        float xv[8] = {v0.x, v0.y, v0.z, v0.w, v1.x, v1.y, v1.z, v1.w};
        float p[8];
#pragma unroll
        for (int h = 0; h < 8; ++h) {
            float s = xv[0] * qr[h][0];
#pragma unroll
            for (int j = 1; j < 8; ++j) s = fmaf(xv[j], qr[h][j], s);
            p[h] = s;
        }
        int b0 = lane & 1, b1 = lane & 2, b2 = lane & 4;
        float t4[4];
#pragma unroll
        for (int i = 0; i < 4; ++i) {
            float send = b0 ? p[i] : p[i + 4];
            float recv = __shfl_xor(send, 1, 64);
            t4[i] = (b0 ? p[i + 4] : p[i]) + recv;
        }
        float u2[2];
#pragma unroll
        for (int i = 0; i < 2; ++i) {
            float send = b1 ? t4[i] : t4[i + 2];
            float recv = __shfl_xor(send, 2, 64);
            u2[i] = (b1 ? t4[i + 2] : t4[i]) + recv;
        }
        float send = b2 ? u2[0] : u2[1];
        float recv = __shfl_xor(send, 4, 64);
        float v = (b2 ? u2[1] : u2[0]) + recv;
        v += __shfl_xor(v, 8, 64);
        v += __shfl_xor(v, 16, 64);
        v += __shfl_xor(v, 32, 64);
        float e = __expf(v);   // logits ~N(0,0.2): un-normalized softmax safe
        lsum += e;
#pragma unroll
        for (int h = 0; h < 8; ++h) {
            int src = ((h & 4) >> 2) | (h & 2) | ((h & 1) << 2);
            float wf = __int_as_float(__builtin_amdgcn_readlane(__float_as_int(e), src));
#pragma unroll
            for (int j = 0; j < 8; ++j) acc[h][j] = fmaf(wf, xv[j], acc[h][j]);
        }
    };

    // prologue: stage tiles 0,1,2 (12 outstanding DMAs)
#pragma unroll
    for (int T = 0; T < 3; ++T) {
        const float* g = gw + (size_t)T * 8 * C_;
        float* d = &smem[wave][T][0];
#pragma unroll
        for (int k = 0; k < 4; ++k)
            dma16(g + k * 256 + lo, d + k * 256);
    }

#pragma unroll 1
    for (int T = 0; T < NT_; ++T) {
        {
            int tn = T + 3 < NT_ ? T + 3 : NT_ - 1;
            const float* g = gw + (size_t)tn * 8 * C_;
            float* d = &smem[wave][(T + 3) & 3][0];
#pragma unroll
            for (int k = 0; k < 4; ++k)
                dma16(g + k * 256 + lo, d + k * 256);
        }
        asm volatile("s_waitcnt vmcnt(12)" ::: "memory");  // tile T landed
        __builtin_amdgcn_sched_barrier(0);
        float* cur = &smem[wave][T & 3][0];
#pragma unroll
        for (int r = 0; r < 2; ++r) {
            float4 v0, v1;
            lds_read2(v0, v1, cur + r * 512 + lo, cur + r * 512 + hi);
            row_body(v0, v1);
        }
    }
    asm volatile("s_waitcnt vmcnt(0)" ::: "memory");  // drain tail dups

    float lw[8];
#pragma unroll
    for (int h = 0; h < 8; ++h) {
        int src = ((h & 4) >> 2) | (h & 2) | ((h & 1) << 2);
        lw[h] = __int_as_float(__builtin_amdgcn_readlane(__float_as_int(lsum), src));
    }

    __syncthreads();
    float* sacc = &smem[0][0][0];   // reuse (8*512 floats)
    for (int w = 0; w < 4; ++w) {
        if (wave == w) {
#pragma unroll
            for (int h = 0; h < 8; ++h) {
                float4 vlo = {acc[h][0], acc[h][1], acc[h][2], acc[h][3]};
                float4 vhi = {acc[h][4], acc[h][5], acc[h][6], acc[h][7]};
                float4* d0 = (float4*)&sacc[h * C_ + lo];
                float4* d1 = (float4*)&sacc[h * C_ + hi];
                if (w == 0) { d0[0] = vlo; d1[0] = vhi; }
                else {
                    float4 a0 = d0[0], a1 = d1[0];
                    a0.x += vlo.x; a0.y += vlo.y; a0.z += vlo.z; a0.w += vlo.w;
                    a1.x += vhi.x; a1.y += vhi.y; a1.z += vhi.z; a1.w += vhi.w;
                    d0[0] = a0; d1[0] = a1;
                }
            }
            if (lane == 0) {
#pragma unroll
                for (int h = 0; h < 8; ++h) {
                    if (w == 0) sl[h] = lw[h]; else sl[h] += lw[h];
                }
            }
        }
        __syncthreads();
    }

    float* aa = ws + WS_AA + b * 4096;
#pragma unroll 16
    for (int k = threadIdx.x; k < 4096; k += 256)
        atomicAdd(&aa[k], sacc[k]);
    if (threadIdx.x < 8)
        atomicAdd(&ws[WS_L + b * 8 + threadIdx.x], sl[threadIdx.x]);
}

// ---------------- K3: pooled (c-split halves) = (1/l) * aa @ Wv ----------------
__global__ void k_proj1(const float* __restrict__ ws, const float* __restrict__ Wv,
                        float* __restrict__ pp) {
    int gid = blockIdx.x * 256 + threadIdx.x;  // [0, 16384)
    int half = gid >> 13;
    int r = gid & 8191;
    int b = r >> 9, o = r & 511, h = o >> 6;
    const float* aa = ws + WS_AA + b * 4096 + h * C_;
    float Li = 1.f / ws[WS_L + b * 8 + h];
    int c0 = half * 256;
    float s = 0.f;
#pragma unroll 16
    for (int c = 0; c < 256; ++c)
        s = fmaf(aa[c0 + c], Wv[(size_t)(c0 + c) * C_ + o], s);
    pp[half * 8192 + r] = s * Li;
}

// ---------------- K4: out = pooled @ Wp + bp ----------------
__global__ void k_proj2(const float* __restrict__ ws, const float* __restrict__ Wp,
                        const float* __restrict__ bp, float* __restrict__ out) {
    int gid = blockIdx.x * 256 + threadIdx.x;  // [0, 8192)
    int b = gid >> 9, o = gid & 511;
    const float* pp = ws + WS_PP + b * 512;
    float s = bp[o];
#pragma unroll 16
    for (int c = 0; c < 512; ++c) {
        float pc = pp[c] + pp[8192 + c];
        s = fmaf(pc, Wp[(size_t)c * C_ + o], s);
    }
    out[(size_t)b * C_ + o] = s;
}

extern "C" void kernel_launch(void* const* d_in, const int* in_sizes, int n_in,
                              void* d_out, int out_size, void* d_ws, size_t ws_size,
                              hipStream_t stream) {
    const float* x   = (const float*)d_in[0];
    const float* cls = (const float*)d_in[1];
    const float* Wq  = (const float*)d_in[2];
    const float* Wk  = (const float*)d_in[3];
    const float* Wv  = (const float*)d_in[4];
    const float* Wp  = (const float*)d_in[5];
    const float* bp  = (const float*)d_in[6];
    float* out = (float*)d_out;
    float* ws  = (float*)d_ws;

    k_prep<<<64, 256, 0, stream>>>(cls, Wq, Wk, ws);
    k_main<<<B_ * CH_, 256, 0, stream>>>(x, ws, CH_);
    k_proj1<<<64, 256, 0, stream>>>(ws, Wv, ws + WS_PP);
    k_proj2<<<32, 256, 0, stream>>>(ws, Wp, bp, out);
}